// Round 13
// baseline (88.363 us; speedup 1.0000x reference)
//
#include <hip/hip_runtime.h>

#define L_COLS 2048
#define NSLOT 64

typedef float vf4 __attribute__((ext_vector_type(4)));

__device__ __forceinline__ float wave_red(float v) {
#pragma unroll
    for (int m = 32; m >= 1; m >>= 1) v += __shfl_xor(v, m, 64);
    return v;
}

// ---------------------------------------------------------------------------
// Init: one wave computes slice bounds from ppm and zeroes the 64 acc slots.
// Python: start = min(where(ppm <= hi)), stop = max(where(ppm >= lo)); [start:stop)
// windows: gaba(2.8,3.2), glx_shape(3.6,3.9), glx_range(3.55,3.95)
// ---------------------------------------------------------------------------
__global__ __launch_bounds__(64) void init_kernel(const float* __restrict__ ppm,
                                                  float* __restrict__ acc,
                                                  int* __restrict__ ob) {
    const int lane = threadIdx.x;
    ((vf4*)acc)[lane] = (vf4){0.f, 0.f, 0.f, 0.f};   // 64 slots x 4 floats

    int mn0 = 0x7fffffff, mn1 = 0x7fffffff, mn2 = 0x7fffffff;
    int mx0 = -1, mx1 = -1, mx2 = -1;
    const vf4* __restrict__ p4 = (const vf4*)ppm;
#pragma unroll
    for (int k = 0; k < L_COLS / 256; ++k) {
        const int j = k * 64 + lane;
        const vf4 pv = p4[j];
        const float ps[4] = {pv.x, pv.y, pv.z, pv.w};
#pragma unroll
        for (int e = 0; e < 4; ++e) {
            const int c = 4 * j + e;
            const float p = ps[e];
            if (p <= 3.2f)  mn0 = min(mn0, c);
            if (p >= 2.8f)  mx0 = max(mx0, c);
            if (p <= 3.9f)  mn1 = min(mn1, c);
            if (p >= 3.6f)  mx1 = max(mx1, c);
            if (p <= 3.95f) mn2 = min(mn2, c);
            if (p >= 3.55f) mx2 = max(mx2, c);
        }
    }
#pragma unroll
    for (int m = 32; m >= 1; m >>= 1) {
        mn0 = min(mn0, __shfl_xor(mn0, m, 64));
        mx0 = max(mx0, __shfl_xor(mx0, m, 64));
        mn1 = min(mn1, __shfl_xor(mn1, m, 64));
        mx1 = max(mx1, __shfl_xor(mx1, m, 64));
        mn2 = min(mn2, __shfl_xor(mn2, m, 64));
        mx2 = max(mx2, __shfl_xor(mx2, m, 64));
    }
    if (lane == 0) {
        ob[0] = mn0; ob[1] = mx0;   // gaba  [lo:hi)
        ob[2] = mn1; ob[3] = mx1;   // glx shape
        ob[4] = mn2; ob[5] = mx2;   // glx range
    }
}

// ---------------------------------------------------------------------------
// One wave handles TWO rows (r, r+4096), chunk loop interleaves 4 independent
// loads per iteration (2x the scheduler-visible ILP of R4) while keeping the
// proven R4 skeleton. If the per-CU miss-tracker wall theory is right this is
// a null result; if per-wave ILP was partially limiting, it gains.
// Pearson via raw moments (norm01 is positive-affine -> invariant).
// Per-row results atomicAdd'ed into slot (row & 63):
//   [score, gaba |d|, glx_range |d|, global |d|]
// ---------------------------------------------------------------------------
__global__ __launch_bounds__(256) void loss_main(const float* __restrict__ x,
                                                 const float* __restrict__ y,
                                                 const int* __restrict__ ob,
                                                 float* __restrict__ acc,
                                                 int half_rows) {
    const int lane = threadIdx.x & 63;
    const int wv   = threadIdx.x >> 6;
    const long r0  = (long)blockIdx.x * 4 + wv;
    const long r1  = r0 + half_rows;

    const int g_lo = ob[0], g_hi = ob[1];
    const int s_lo = ob[2], s_hi = ob[3];
    const int r_lo = ob[4], r_hi = ob[5];
    const int lo_any = min(min(g_lo, s_lo), r_lo);
    const int hi_any = max(max(g_hi, s_hi), r_hi);

    const vf4* __restrict__ x0 = (const vf4*)(x + r0 * L_COLS);
    const vf4* __restrict__ y0 = (const vf4*)(y + r0 * L_COLS);
    const vf4* __restrict__ x1 = (const vf4*)(x + r1 * L_COLS);
    const vf4* __restrict__ y1 = (const vf4*)(y + r1 * L_COLS);

    float gl0 = 0.f, gl1 = 0.f;
    float a_sx0 = 0, a_sy0 = 0, a_xy0 = 0, a_xx0 = 0, a_yy0 = 0, a_mae0 = 0;
    float b_sx0 = 0, b_sy0 = 0, b_xy0 = 0, b_xx0 = 0, b_yy0 = 0, r_mae0 = 0;
    float a_sx1 = 0, a_sy1 = 0, a_xy1 = 0, a_xx1 = 0, a_yy1 = 0, a_mae1 = 0;
    float b_sx1 = 0, b_sy1 = 0, b_xy1 = 0, b_xx1 = 0, b_yy1 = 0, r_mae1 = 0;

#pragma unroll
    for (int k = 0; k < 8; ++k) {
        const int j = k * 64 + lane;
        const vf4 xv0 = x0[j];
        const vf4 yv0 = y0[j];
        const vf4 xv1 = x1[j];
        const vf4 yv1 = y1[j];

        const float e0 = fabsf(xv0.x - yv0.x), e1 = fabsf(xv0.y - yv0.y);
        const float e2 = fabsf(xv0.z - yv0.z), e3 = fabsf(xv0.w - yv0.w);
        gl0 += (e0 + e1) + (e2 + e3);
        const float f0 = fabsf(xv1.x - yv1.x), f1 = fabsf(xv1.y - yv1.y);
        const float f2 = fabsf(xv1.z - yv1.z), f3 = fabsf(xv1.w - yv1.w);
        gl1 += (f0 + f1) + (f2 + f3);

        if (k * 256 < hi_any && k * 256 + 256 > lo_any) {
            const float xs0[4] = {xv0.x, xv0.y, xv0.z, xv0.w};
            const float ys0[4] = {yv0.x, yv0.y, yv0.z, yv0.w};
            const float ds0[4] = {e0, e1, e2, e3};
            const float xs1[4] = {xv1.x, xv1.y, xv1.z, xv1.w};
            const float ys1[4] = {yv1.x, yv1.y, yv1.z, yv1.w};
            const float ds1[4] = {f0, f1, f2, f3};
#pragma unroll
            for (int e = 0; e < 4; ++e) {
                const int c = 4 * j + e;
                const bool in_g = (c >= g_lo && c < g_hi);
                const bool in_s = (c >= s_lo && c < s_hi);
                const bool in_r = (c >= r_lo && c < r_hi);
                const float xa = xs0[e], ya = ys0[e];
                const float xb = xs1[e], yb = ys1[e];
                if (in_g) {
                    a_sx0 += xa; a_sy0 += ya; a_xy0 += xa * ya;
                    a_xx0 += xa * xa; a_yy0 += ya * ya; a_mae0 += ds0[e];
                    a_sx1 += xb; a_sy1 += yb; a_xy1 += xb * yb;
                    a_xx1 += xb * xb; a_yy1 += yb * yb; a_mae1 += ds1[e];
                }
                if (in_s) {
                    b_sx0 += xa; b_sy0 += ya; b_xy0 += xa * ya;
                    b_xx0 += xa * xa; b_yy0 += ya * ya;
                    b_sx1 += xb; b_sy1 += yb; b_xy1 += xb * yb;
                    b_xx1 += xb * xb; b_yy1 += yb * yb;
                }
                if (in_r) { r_mae0 += ds0[e]; r_mae1 += ds1[e]; }
            }
        }
    }

    // ---- row 0 reduction + emit
    gl0    = wave_red(gl0);
    a_sx0  = wave_red(a_sx0);  a_sy0 = wave_red(a_sy0);
    a_xy0  = wave_red(a_xy0);  a_xx0 = wave_red(a_xx0);  a_yy0 = wave_red(a_yy0);
    a_mae0 = wave_red(a_mae0);
    b_sx0  = wave_red(b_sx0);  b_sy0 = wave_red(b_sy0);
    b_xy0  = wave_red(b_xy0);  b_xx0 = wave_red(b_xx0);  b_yy0 = wave_red(b_yy0);
    r_mae0 = wave_red(r_mae0);

    const float ng = (float)(g_hi - g_lo);
    const float ns = (float)(s_hi - s_lo);
    if (lane == 0) {
        const float covA = a_xy0 - a_sx0 * a_sy0 / ng;
        const float vAx  = a_xx0 - a_sx0 * a_sx0 / ng;
        const float vAy  = a_yy0 - a_sy0 * a_sy0 / ng;
        const float scoreA = covA * rsqrtf(vAx * vAy);
        const float covB = b_xy0 - b_sx0 * b_sy0 / ns;
        const float vBx  = b_xx0 - b_sx0 * b_sx0 / ns;
        const float vBy  = b_yy0 - b_sy0 * b_sy0 / ns;
        const float scoreB = covB * rsqrtf(vBx * vBy);
        float* slot = acc + 4 * ((int)r0 & (NSLOT - 1));
        atomicAdd(&slot[0], 0.6f * scoreA + 0.4f * scoreB);
        atomicAdd(&slot[1], a_mae0);
        atomicAdd(&slot[2], r_mae0);
        atomicAdd(&slot[3], gl0);
    }

    // ---- row 1 reduction + emit
    gl1    = wave_red(gl1);
    a_sx1  = wave_red(a_sx1);  a_sy1 = wave_red(a_sy1);
    a_xy1  = wave_red(a_xy1);  a_xx1 = wave_red(a_xx1);  a_yy1 = wave_red(a_yy1);
    a_mae1 = wave_red(a_mae1);
    b_sx1  = wave_red(b_sx1);  b_sy1 = wave_red(b_sy1);
    b_xy1  = wave_red(b_xy1);  b_xx1 = wave_red(b_xx1);  b_yy1 = wave_red(b_yy1);
    r_mae1 = wave_red(r_mae1);

    if (lane == 0) {
        const float covA = a_xy1 - a_sx1 * a_sy1 / ng;
        const float vAx  = a_xx1 - a_sx1 * a_sx1 / ng;
        const float vAy  = a_yy1 - a_sy1 * a_sy1 / ng;
        const float scoreA = covA * rsqrtf(vAx * vAy);
        const float covB = b_xy1 - b_sx1 * b_sy1 / ns;
        const float vBx  = b_xx1 - b_sx1 * b_sx1 / ns;
        const float vBy  = b_yy1 - b_sy1 * b_sy1 / ns;
        const float scoreB = covB * rsqrtf(vBx * vBy);
        float* slot = acc + 4 * ((int)r1 & (NSLOT - 1));
        atomicAdd(&slot[0], 0.6f * scoreA + 0.4f * scoreB);
        atomicAdd(&slot[1], a_mae1);
        atomicAdd(&slot[2], r_mae1);
        atomicAdd(&slot[3], gl1);
    }
}

// ---------------------------------------------------------------------------
// Finalize: one wave reduces the 64 slots and emits the scalar loss.
// ---------------------------------------------------------------------------
__global__ __launch_bounds__(64) void finalize_kernel(const float* __restrict__ acc,
                                                      const int* __restrict__ ob,
                                                      int Brows, float* __restrict__ out) {
    const int lane = threadIdx.x;
    vf4 v = ((const vf4*)acc)[lane];
    v.x = wave_red(v.x);
    v.y = wave_red(v.y);
    v.z = wave_red(v.z);
    v.w = wave_red(v.w);
    if (lane == 0) {
        const float ng = (float)(ob[1] - ob[0]);
        const float nr = (float)(ob[5] - ob[4]);
        const float Bf = (float)Brows;
        const float shape_loss = 1.f - v.x / Bf;
        const float gaba_mae = v.y / (Bf * ng);
        const float glx_mae  = v.z / (Bf * nr);
        const float glob_mae = v.w / (Bf * (float)L_COLS);
        const float range_loss = (gaba_mae * 6.f + glx_mae * 3.f + glob_mae) * 0.1f;
        out[0] = shape_loss + range_loss * 0.5f;
    }
}

extern "C" void kernel_launch(void* const* d_in, const int* in_sizes, int n_in,
                              void* d_out, int out_size, void* d_ws, size_t ws_size,
                              hipStream_t stream) {
    const float* x   = (const float*)d_in[0];
    const float* ppm = (const float*)d_in[1];
    const float* y   = (const float*)d_in[2];
    const int L = in_sizes[1];          // 2048 (== L_COLS)
    const int Brows = in_sizes[0] / L;  // 8192

    float* acc = (float*)d_ws;                    // 64 slots x 4 floats = 1 KB
    int*   ob  = (int*)((char*)d_ws + 1024);      // 6 ints of bounds

    init_kernel<<<1, 64, 0, stream>>>(ppm, acc, ob);
    loss_main<<<Brows / 8, 256, 0, stream>>>(x, y, ob, acc, Brows / 2);
    finalize_kernel<<<1, 64, 0, stream>>>(acc, ob, Brows, (float*)d_out);
}

// Round 14
// 82.350 us; speedup vs baseline: 1.0730x; 1.0730x over previous
//
#include <hip/hip_runtime.h>

#define L_COLS 2048
#define NSLOT 64

typedef float vf4 __attribute__((ext_vector_type(4)));

__device__ __forceinline__ float wave_red(float v) {
#pragma unroll
    for (int m = 32; m >= 1; m >>= 1) v += __shfl_xor(v, m, 64);
    return v;
}

// ---------------------------------------------------------------------------
// Init: one wave computes slice bounds from ppm and zeroes the 64 acc slots.
// Python: start = min(where(ppm <= hi)), stop = max(where(ppm >= lo)); [start:stop)
// windows: gaba(2.8,3.2), glx_shape(3.6,3.9), glx_range(3.55,3.95)
// ---------------------------------------------------------------------------
__global__ __launch_bounds__(64) void init_kernel(const float* __restrict__ ppm,
                                                  float* __restrict__ acc,
                                                  int* __restrict__ ob) {
    const int lane = threadIdx.x;
    ((vf4*)acc)[lane] = (vf4){0.f, 0.f, 0.f, 0.f};   // 64 slots x 4 floats

    int mn0 = 0x7fffffff, mn1 = 0x7fffffff, mn2 = 0x7fffffff;
    int mx0 = -1, mx1 = -1, mx2 = -1;
    const vf4* __restrict__ p4 = (const vf4*)ppm;
#pragma unroll
    for (int k = 0; k < L_COLS / 256; ++k) {
        const int j = k * 64 + lane;
        const vf4 pv = p4[j];
        const float ps[4] = {pv.x, pv.y, pv.z, pv.w};
#pragma unroll
        for (int e = 0; e < 4; ++e) {
            const int c = 4 * j + e;
            const float p = ps[e];
            if (p <= 3.2f)  mn0 = min(mn0, c);
            if (p >= 2.8f)  mx0 = max(mx0, c);
            if (p <= 3.9f)  mn1 = min(mn1, c);
            if (p >= 3.6f)  mx1 = max(mx1, c);
            if (p <= 3.95f) mn2 = min(mn2, c);
            if (p >= 3.55f) mx2 = max(mx2, c);
        }
    }
#pragma unroll
    for (int m = 32; m >= 1; m >>= 1) {
        mn0 = min(mn0, __shfl_xor(mn0, m, 64));
        mx0 = max(mx0, __shfl_xor(mx0, m, 64));
        mn1 = min(mn1, __shfl_xor(mn1, m, 64));
        mx1 = max(mx1, __shfl_xor(mx1, m, 64));
        mn2 = min(mn2, __shfl_xor(mn2, m, 64));
        mx2 = max(mx2, __shfl_xor(mx2, m, 64));
    }
    if (lane == 0) {
        ob[0] = mn0; ob[1] = mx0;   // gaba  [lo:hi)
        ob[2] = mn1; ob[3] = mx1;   // glx shape
        ob[4] = mn2; ob[5] = mx2;   // glx range
    }
}

// consume one 256-col chunk (compile-time K); window test is wave-uniform
#define CONSUME(K, XV, YV)                                                    \
    {                                                                         \
        const float d0 = fabsf(XV.x - YV.x), d1 = fabsf(XV.y - YV.y);         \
        const float d2 = fabsf(XV.z - YV.z), d3 = fabsf(XV.w - YV.w);         \
        gl += (d0 + d1) + (d2 + d3);                                          \
        if (K * 256 < hi_any && K * 256 + 256 > lo_any) {                     \
            const float xs[4] = {XV.x, XV.y, XV.z, XV.w};                     \
            const float ys[4] = {YV.x, YV.y, YV.z, YV.w};                     \
            const float ds[4] = {d0, d1, d2, d3};                             \
            _Pragma("unroll")                                                 \
            for (int e = 0; e < 4; ++e) {                                     \
                const int c = K * 256 + 4 * lane + e;                         \
                const float xe = xs[e], ye = ys[e];                           \
                if (c >= g_lo && c < g_hi) {                                  \
                    a_sx += xe; a_sy += ye; a_xy += xe * ye;                  \
                    a_xx += xe * xe; a_yy += ye * ye; a_mae += ds[e];         \
                }                                                             \
                if (c >= s_lo && c < s_hi) {                                  \
                    b_sx += xe; b_sy += ye; b_xy += xe * ye;                  \
                    b_xx += xe * xe; b_yy += ye * ye;                         \
                }                                                             \
                if (c >= r_lo && c < r_hi) r_mae += ds[e];                    \
            }                                                                 \
        }                                                                     \
    }

// ---------------------------------------------------------------------------
// One wave per row (R4 skeleton). The 16 row loads are issued inside ONE asm
// block with 16 early-clobber vf4 outputs: regalloc CANNOT re-serialize them
// (the R4/R6/R13 failure mode, proven by VGPR_Count=48/68). 16 KB genuinely
// in flight per wave; pipelined consume via vmcnt(8)/vmcnt(0) + sched_barrier
// (guide rule #18: fence register-only consumes behind inline-asm waitcnt).
// Pearson via raw moments (norm01 is positive-affine -> invariant).
// ---------------------------------------------------------------------------
__global__ __launch_bounds__(256, 4) void loss_main(const float* __restrict__ x,
                                                    const float* __restrict__ y,
                                                    const int* __restrict__ ob,
                                                    float* __restrict__ acc) {
    const int lane = threadIdx.x & 63;
    const int wv   = threadIdx.x >> 6;
    const long row = (long)blockIdx.x * 4 + wv;

    const int g_lo = ob[0], g_hi = ob[1];
    const int s_lo = ob[2], s_hi = ob[3];
    const int r_lo = ob[4], r_hi = ob[5];
    const int lo_any = min(min(g_lo, s_lo), r_lo);
    const int hi_any = max(max(g_hi, s_hi), r_hi);

    const float* xpa = x + row * L_COLS + lane * 4;
    const float* ypa = y + row * L_COLS + lane * 4;
    const float* xpb = xpa + 1024;        // cols 1024.. (chunks 4-7)
    const float* ypb = ypa + 1024;

    vf4 x0, x1, x2, x3, x4, x5, x6, x7;
    vf4 y0, y1, y2, y3, y4, y5, y6, y7;

    // 16 loads issued back-to-back; outputs pinned in 64 VGPRs.
    asm volatile(
        "global_load_dwordx4 %0, %16, off\n\t"
        "global_load_dwordx4 %1, %16, off offset:1024\n\t"
        "global_load_dwordx4 %2, %16, off offset:2048\n\t"
        "global_load_dwordx4 %3, %16, off offset:3072\n\t"
        "global_load_dwordx4 %4, %17, off\n\t"
        "global_load_dwordx4 %5, %17, off offset:1024\n\t"
        "global_load_dwordx4 %6, %17, off offset:2048\n\t"
        "global_load_dwordx4 %7, %17, off offset:3072\n\t"
        "global_load_dwordx4 %8, %18, off\n\t"
        "global_load_dwordx4 %9, %18, off offset:1024\n\t"
        "global_load_dwordx4 %10, %18, off offset:2048\n\t"
        "global_load_dwordx4 %11, %18, off offset:3072\n\t"
        "global_load_dwordx4 %12, %19, off\n\t"
        "global_load_dwordx4 %13, %19, off offset:1024\n\t"
        "global_load_dwordx4 %14, %19, off offset:2048\n\t"
        "global_load_dwordx4 %15, %19, off offset:3072\n\t"
        : "=&v"(x0), "=&v"(x1), "=&v"(x2), "=&v"(x3),
          "=&v"(y0), "=&v"(y1), "=&v"(y2), "=&v"(y3),
          "=&v"(x4), "=&v"(x5), "=&v"(x6), "=&v"(x7),
          "=&v"(y4), "=&v"(y5), "=&v"(y6), "=&v"(y7)
        : "v"(xpa), "v"(ypa), "v"(xpb), "v"(ypb));

    float gl = 0.f;
    float a_sx = 0, a_sy = 0, a_xy = 0, a_xx = 0, a_yy = 0, a_mae = 0;
    float b_sx = 0, b_sy = 0, b_xy = 0, b_xx = 0, b_yy = 0;
    float r_mae = 0;

    // first 8 loads (chunks 0-3) landed; last 8 still in flight
    asm volatile("s_waitcnt vmcnt(8)" ::: "memory");
    __builtin_amdgcn_sched_barrier(0);
    CONSUME(0, x0, y0)
    CONSUME(1, x1, y1)
    CONSUME(2, x2, y2)
    CONSUME(3, x3, y3)

    asm volatile("s_waitcnt vmcnt(0)" ::: "memory");
    __builtin_amdgcn_sched_barrier(0);
    CONSUME(4, x4, y4)
    CONSUME(5, x5, y5)
    CONSUME(6, x6, y6)
    CONSUME(7, x7, y7)

    gl    = wave_red(gl);
    a_sx  = wave_red(a_sx);  a_sy = wave_red(a_sy);
    a_xy  = wave_red(a_xy);  a_xx = wave_red(a_xx);  a_yy = wave_red(a_yy);
    a_mae = wave_red(a_mae);
    b_sx  = wave_red(b_sx);  b_sy = wave_red(b_sy);
    b_xy  = wave_red(b_xy);  b_xx = wave_red(b_xx);  b_yy = wave_red(b_yy);
    r_mae = wave_red(r_mae);

    if (lane == 0) {
        const float ng = (float)(g_hi - g_lo);
        const float ns = (float)(s_hi - s_lo);
        const float covA = a_xy - a_sx * a_sy / ng;
        const float vAx  = a_xx - a_sx * a_sx / ng;
        const float vAy  = a_yy - a_sy * a_sy / ng;
        const float scoreA = covA * rsqrtf(vAx * vAy);
        const float covB = b_xy - b_sx * b_sy / ns;
        const float vBx  = b_xx - b_sx * b_sx / ns;
        const float vBy  = b_yy - b_sy * b_sy / ns;
        const float scoreB = covB * rsqrtf(vBx * vBy);
        float* slot = acc + 4 * ((int)row & (NSLOT - 1));
        atomicAdd(&slot[0], 0.6f * scoreA + 0.4f * scoreB);
        atomicAdd(&slot[1], a_mae);
        atomicAdd(&slot[2], r_mae);
        atomicAdd(&slot[3], gl);
    }
}

// ---------------------------------------------------------------------------
// Finalize: one wave reduces the 64 slots and emits the scalar loss.
// ---------------------------------------------------------------------------
__global__ __launch_bounds__(64) void finalize_kernel(const float* __restrict__ acc,
                                                      const int* __restrict__ ob,
                                                      int Brows, float* __restrict__ out) {
    const int lane = threadIdx.x;
    vf4 v = ((const vf4*)acc)[lane];
    v.x = wave_red(v.x);
    v.y = wave_red(v.y);
    v.z = wave_red(v.z);
    v.w = wave_red(v.w);
    if (lane == 0) {
        const float ng = (float)(ob[1] - ob[0]);
        const float nr = (float)(ob[5] - ob[4]);
        const float Bf = (float)Brows;
        const float shape_loss = 1.f - v.x / Bf;
        const float gaba_mae = v.y / (Bf * ng);
        const float glx_mae  = v.z / (Bf * nr);
        const float glob_mae = v.w / (Bf * (float)L_COLS);
        const float range_loss = (gaba_mae * 6.f + glx_mae * 3.f + glob_mae) * 0.1f;
        out[0] = shape_loss + range_loss * 0.5f;
    }
}

extern "C" void kernel_launch(void* const* d_in, const int* in_sizes, int n_in,
                              void* d_out, int out_size, void* d_ws, size_t ws_size,
                              hipStream_t stream) {
    const float* x   = (const float*)d_in[0];
    const float* ppm = (const float*)d_in[1];
    const float* y   = (const float*)d_in[2];
    const int L = in_sizes[1];          // 2048 (== L_COLS)
    const int Brows = in_sizes[0] / L;  // 8192

    float* acc = (float*)d_ws;                    // 64 slots x 4 floats = 1 KB
    int*   ob  = (int*)((char*)d_ws + 1024);      // 6 ints of bounds

    init_kernel<<<1, 64, 0, stream>>>(ppm, acc, ob);
    loss_main<<<Brows / 4, 256, 0, stream>>>(x, y, ob, acc);
    finalize_kernel<<<1, 64, 0, stream>>>(acc, ob, Brows, (float*)d_out);
}

// Round 15
// 46.675 us; speedup vs baseline: 1.8931x; 1.7643x over previous
//
#include <hip/hip_runtime.h>

#define L_COLS 2048

typedef float vf4 __attribute__((ext_vector_type(4)));

__device__ __forceinline__ float wave_red(float v) {
#pragma unroll
    for (int m = 32; m >= 1; m >>= 1) v += __shfl_xor(v, m, 64);
    return v;
}

// ---------------------------------------------------------------------------
// Init: one wave computes slice bounds from ppm (register min/max + shfl) and
// zeroes the accumulators.
// Python: start = min(where(ppm <= hi)), stop = max(where(ppm >= lo)); [start:stop)
// windows: gaba(2.8,3.2), glx_shape(3.6,3.9), glx_range(3.55,3.95)
// ---------------------------------------------------------------------------
__global__ __launch_bounds__(64) void init_kernel(const float* __restrict__ ppm,
                                                  float* __restrict__ acc,
                                                  int* __restrict__ ob) {
    const int lane = threadIdx.x;
    if (lane < 4) acc[lane] = 0.f;

    int mn0 = 0x7fffffff, mn1 = 0x7fffffff, mn2 = 0x7fffffff;
    int mx0 = -1, mx1 = -1, mx2 = -1;
    const vf4* __restrict__ p4 = (const vf4*)ppm;
#pragma unroll
    for (int k = 0; k < L_COLS / 256; ++k) {
        const int j = k * 64 + lane;
        const vf4 pv = p4[j];
        const float ps[4] = {pv.x, pv.y, pv.z, pv.w};
#pragma unroll
        for (int e = 0; e < 4; ++e) {
            const int c = 4 * j + e;
            const float p = ps[e];
            if (p <= 3.2f)  mn0 = min(mn0, c);
            if (p >= 2.8f)  mx0 = max(mx0, c);
            if (p <= 3.9f)  mn1 = min(mn1, c);
            if (p >= 3.6f)  mx1 = max(mx1, c);
            if (p <= 3.95f) mn2 = min(mn2, c);
            if (p >= 3.55f) mx2 = max(mx2, c);
        }
    }
#pragma unroll
    for (int m = 32; m >= 1; m >>= 1) {
        mn0 = min(mn0, __shfl_xor(mn0, m, 64));
        mx0 = max(mx0, __shfl_xor(mx0, m, 64));
        mn1 = min(mn1, __shfl_xor(mn1, m, 64));
        mx1 = max(mx1, __shfl_xor(mx1, m, 64));
        mn2 = min(mn2, __shfl_xor(mn2, m, 64));
        mx2 = max(mx2, __shfl_xor(mx2, m, 64));
    }
    if (lane == 0) {
        ob[0] = mn0; ob[1] = mx0;   // gaba  [lo:hi)
        ob[2] = mn1; ob[3] = mx1;   // glx shape
        ob[4] = mn2; ob[5] = mx2;   // glx range
    }
}

// ---------------------------------------------------------------------------
// One wave per row (best measured structure: 46.3 us total, ~2.98 TB/s read =
// 95% of the read-side of the 6.29 TB/s D2D copy ceiling; per-CU read path is
// the wall — R12 DMA and R14 forced-asm depth both regressed).
// Pearson via raw moments (norm01 is positive-affine -> invariant).
// acc[0]=Σ(0.6*r_gaba+0.4*r_glx), acc[1]=Σ|d| gaba, acc[2]=Σ|d| glx_range,
// acc[3]=Σ|d| global
// ---------------------------------------------------------------------------
__global__ __launch_bounds__(256, 2) void loss_main(const float* __restrict__ x,
                                                    const float* __restrict__ y,
                                                    const int* __restrict__ ob,
                                                    float* __restrict__ acc) {
    const int lane = threadIdx.x & 63;
    const int wv   = threadIdx.x >> 6;
    const long row = (long)blockIdx.x * 4 + wv;

    const int g_lo = ob[0], g_hi = ob[1];
    const int s_lo = ob[2], s_hi = ob[3];
    const int r_lo = ob[4], r_hi = ob[5];
    const int lo_any = min(min(g_lo, s_lo), r_lo);
    const int hi_any = max(max(g_hi, s_hi), r_hi);

    const vf4* __restrict__ x4 = (const vf4*)(x + row * L_COLS);
    const vf4* __restrict__ y4 = (const vf4*)(y + row * L_COLS);

    vf4 xr[8], yr[8];
#pragma unroll
    for (int k = 0; k < 8; ++k) xr[k] = x4[k * 64 + lane];
#pragma unroll
    for (int k = 0; k < 8; ++k) yr[k] = y4[k * 64 + lane];

    float gl = 0.f;
    float a_sx = 0, a_sy = 0, a_xy = 0, a_xx = 0, a_yy = 0, a_mae = 0;
    float b_sx = 0, b_sy = 0, b_xy = 0, b_xx = 0, b_yy = 0;
    float r_mae = 0;

#pragma unroll
    for (int k = 0; k < 8; ++k) {
        const vf4 xv = xr[k];
        const vf4 yv = yr[k];
        const float d0 = fabsf(xv.x - yv.x), d1 = fabsf(xv.y - yv.y);
        const float d2 = fabsf(xv.z - yv.z), d3 = fabsf(xv.w - yv.w);
        gl += (d0 + d1) + (d2 + d3);

        // wave-uniform: can this 256-col chunk touch any window?
        if (k * 256 < hi_any && k * 256 + 256 > lo_any) {
            const float xs[4] = {xv.x, xv.y, xv.z, xv.w};
            const float ys[4] = {yv.x, yv.y, yv.z, yv.w};
            const float ds[4] = {d0, d1, d2, d3};
#pragma unroll
            for (int e = 0; e < 4; ++e) {
                const int c = k * 256 + 4 * lane + e;
                const float xe = xs[e], ye = ys[e];
                if (c >= g_lo && c < g_hi) {
                    a_sx += xe; a_sy += ye; a_xy += xe * ye;
                    a_xx += xe * xe; a_yy += ye * ye; a_mae += ds[e];
                }
                if (c >= s_lo && c < s_hi) {
                    b_sx += xe; b_sy += ye; b_xy += xe * ye;
                    b_xx += xe * xe; b_yy += ye * ye;
                }
                if (c >= r_lo && c < r_hi) r_mae += ds[e];
            }
        }
    }

    gl    = wave_red(gl);
    a_sx  = wave_red(a_sx);  a_sy = wave_red(a_sy);
    a_xy  = wave_red(a_xy);  a_xx = wave_red(a_xx);  a_yy = wave_red(a_yy);
    a_mae = wave_red(a_mae);
    b_sx  = wave_red(b_sx);  b_sy = wave_red(b_sy);
    b_xy  = wave_red(b_xy);  b_xx = wave_red(b_xx);  b_yy = wave_red(b_yy);
    r_mae = wave_red(r_mae);

    __shared__ float part[4][4];
    if (lane == 0) {
        const float ng = (float)(g_hi - g_lo);
        const float ns = (float)(s_hi - s_lo);
        const float covA = a_xy - a_sx * a_sy / ng;
        const float vAx  = a_xx - a_sx * a_sx / ng;
        const float vAy  = a_yy - a_sy * a_sy / ng;
        const float scoreA = covA * rsqrtf(vAx * vAy);
        const float covB = b_xy - b_sx * b_sy / ns;
        const float vBx  = b_xx - b_sx * b_sx / ns;
        const float vBy  = b_yy - b_sy * b_sy / ns;
        const float scoreB = covB * rsqrtf(vBx * vBy);
        part[wv][0] = 0.6f * scoreA + 0.4f * scoreB;
        part[wv][1] = a_mae;
        part[wv][2] = r_mae;
        part[wv][3] = gl;
    }
    __syncthreads();
    if (threadIdx.x < 4) {
        const float s = part[0][threadIdx.x] + part[1][threadIdx.x] +
                        part[2][threadIdx.x] + part[3][threadIdx.x];
        atomicAdd(&acc[threadIdx.x], s);
    }
}

// ---------------------------------------------------------------------------
// Finalize: single thread combines partial sums into the scalar loss.
// ---------------------------------------------------------------------------
__global__ void finalize_kernel(const float* __restrict__ acc, const int* __restrict__ ob,
                                int Brows, float* __restrict__ out) {
    const float ng = (float)(ob[1] - ob[0]);
    const float nr = (float)(ob[5] - ob[4]);
    const float Bf = (float)Brows;
    const float shape_loss = 1.f - acc[0] / Bf;
    const float gaba_mae = acc[1] / (Bf * ng);
    const float glx_mae  = acc[2] / (Bf * nr);
    const float glob_mae = acc[3] / (Bf * (float)L_COLS);
    const float range_loss = (gaba_mae * 6.f + glx_mae * 3.f + glob_mae) * 0.1f;
    out[0] = shape_loss + range_loss * 0.5f;
}

extern "C" void kernel_launch(void* const* d_in, const int* in_sizes, int n_in,
                              void* d_out, int out_size, void* d_ws, size_t ws_size,
                              hipStream_t stream) {
    const float* x   = (const float*)d_in[0];
    const float* ppm = (const float*)d_in[1];
    const float* y   = (const float*)d_in[2];
    const int L = in_sizes[1];          // 2048 (== L_COLS)
    const int Brows = in_sizes[0] / L;  // 8192

    float* acc = (float*)d_ws;                 // 4 floats of accumulators
    int*   ob  = (int*)((char*)d_ws + 64);     // 6 ints of bounds

    init_kernel<<<1, 64, 0, stream>>>(ppm, acc, ob);
    loss_main<<<Brows / 4, 256, 0, stream>>>(x, y, ob, acc);
    finalize_kernel<<<1, 1, 0, stream>>>(acc, ob, Brows, (float*)d_out);
}